// Round 18
// baseline (41.762 us; speedup 1.0000x reference)
//
#include <hip/hip_runtime.h>

typedef _Float16 f16x4 __attribute__((ext_vector_type(4)));
typedef _Float16 f16x8 __attribute__((ext_vector_type(8)));
typedef __fp16 fp16x2 __attribute__((ext_vector_type(2)));   // cvt_pkrtz return type
typedef float f32x4 __attribute__((ext_vector_type(4)));
typedef float f32x2 __attribute__((ext_vector_type(2)));

#define NBUCKETS 256
#define SSTR 88              // row stride in halves (16B-aligned rows for b128)
#define NROWS 74             // staged rows (64 outputs + 10 halo)
#define NLD 12               // staging float4 loads per thread (2960/256 = 11.6)

__device__ __forceinline__ f16x4 cvt4(f32x4 a)
{
    union { fp16x2 h2[2]; f16x4 f; } u;
    u.h2[0] = __builtin_amdgcn_cvt_pkrtz(a[0], a[1]);
    u.h2[1] = __builtin_amdgcn_cvt_pkrtz(a[2], a[3]);
    return u.f;
}

// ---- main: TWO vertically-adjacent 64x64 regions per block, 4 waves.
// Region-2 loads issued BEFORE region-1 compute (register prefetch, single LDS buf):
//   stage R1 | barrier | issue R2 loads + build weights | compute R1 | barrier |
//   write R2 | barrier | compute R2 | scattered bucket atomic.
// H-pass: one mfma_f32_16x16x32_f16 per quantity; D-frag (row=4g+j) feeds vertical
// 16x16x16 B-frags in registers (validated R3/R5-R17). Weights in-block (R15+).
__global__ __launch_bounds__(256, 4) void ssim_main(
    const float* __restrict__ raw, const float* __restrict__ dst,
    const float* __restrict__ win, float* __restrict__ buckets, int chunkw)
{
    __shared__ __align__(16) _Float16 sr[NROWS * SSTR];
    __shared__ __align__(16) _Float16 sd[NROWS * SSTR];
    __shared__ float w1s[11];

    const int tid = threadIdx.x;
    const int wv = tid >> 6;           // wave = 16-wide x-strip
    const int lane = tid & 63;
    const int g = lane >> 4;
    const int ln = lane & 15;
    const int nt = wv;

    // XCD-bijective swizzle (nwg % 8 == 0): contiguous runs per XCD (R17-validated)
    const int wg = blockIdx.x;
    const int sw = (wg & 7) * chunkw + (wg >> 3);
    const int bx = sw & 7;
    const int byp = (sw >> 3) & 3;     // region-pair y index
    const int bz = sw >> 5;

    const int gx0 = bx * 64;
    const int yb1 = byp * 128;         // region 1 first input row
    const int yb2 = yb1 + 64;          // region 2 first input row
    const long ioff = (long)bz * (512 * 512);
    const float* rb = raw + ioff;
    const float* db = dst + ioff;

    // 1D gaussian row-sums -> LDS (11 threads; covered by staging barrier)
    if (tid >= 245) {
        int i = tid - 245;             // 0..10
        float s = 0.f;
#pragma unroll
        for (int j = 0; j < 11; ++j) s += win[i * 11 + j];
        w1s[i] = s;
    }

    // ---- staging helpers: 2960 tasks = 74 rows x {r,d} x 20 float4 chunks ----
#define ISSUE_F(FV, YB)                                                       \
    { _Pragma("unroll")                                                       \
      for (int k = 0; k < NLD; ++k) {                                         \
          int t = tid + 256 * k;                                              \
          if (k < NLD - 1 || t < 2960) {                                      \
              int chunk = t % 20;                                             \
              int sub = t / 20;                                               \
              int row = sub >> 1;                                             \
              const float* src = (sub & 1) ? db : rb;                         \
              FV[k] = *reinterpret_cast<const float4*>(                       \
                  src + (long)((YB) + row) * 512 + gx0 + 4 * chunk);          \
          } } }
#define ISSUE_C(FV, YB)                                                       \
    { _Pragma("unroll")                                                       \
      for (int k = 0; k < NLD; ++k) {                                         \
          int t = tid + 256 * k;                                              \
          if (k < NLD - 1 || t < 2960) {                                      \
              int chunk = t % 20;                                             \
              int sub = t / 20;                                               \
              int row = sub >> 1;                                             \
              int gy = (YB) + row; if (gy > 511) gy = 511;                    \
              int gxc = gx0 + 4 * chunk; if (gxc > 508) gxc = 508;            \
              const float* src = (sub & 1) ? db : rb;                         \
              FV[k] = *reinterpret_cast<const float4*>(src + (long)gy * 512 + gxc); \
          } } }
#define WRITE_LDS(FV)                                                         \
    { _Pragma("unroll")                                                       \
      for (int k = 0; k < NLD; ++k) {                                         \
          int t = tid + 256 * k;                                              \
          if (k < NLD - 1 || t < 2960) {                                      \
              int chunk = t % 20;                                             \
              int sub = t / 20;                                               \
              int row = sub >> 1;                                             \
              _Float16* dstp = ((sub & 1) ? sd : sr) + row * SSTR + chunk * 4; \
              union { fp16x2 h2[2]; uint2 u; } pk;                            \
              pk.h2[0] = __builtin_amdgcn_cvt_pkrtz(FV[k].x, FV[k].y);        \
              pk.h2[1] = __builtin_amdgcn_cvt_pkrtz(FV[k].z, FV[k].w);        \
              *reinterpret_cast<uint2*>(dstp) = pk.u;                         \
          } } }

    const bool xfast = (gx0 < 448);

    // ---- stage region 1 ----
    {
        float4 fv[NLD];
        if (xfast) ISSUE_F(fv, yb1) else ISSUE_C(fv, yb1)   // yb1 <= 384: rows in-image
        WRITE_LDS(fv)
    }
    __syncthreads();

    // ---- prefetch region 2 (hides under region-1 compute) ----
    float4 fv2[NLD];
    if (xfast && yb2 < 448) ISSUE_F(fv2, yb2) else ISSUE_C(fv2, yb2)

    // ---- per-lane weight fragments (banded, translation-invariant; R15-validated) ----
    f16x4 wf0, wf1;
    f16x8 wh;
    {
        float v[8];
#pragma unroll
        for (int kk = 0; kk < 2; ++kk) {
            int ib = 4 * g + 16 * kk - ln;
#pragma unroll
            for (int j = 0; j < 4; ++j) {
                int idx = ib + j;
                int ci = idx < 0 ? 0 : (idx > 10 ? 10 : idx);
                float t = w1s[ci];
                v[kk * 4 + j] = (idx >= 0 && idx <= 10) ? t : 0.f;
            }
        }
        wf0 = f16x4{(_Float16)v[0], (_Float16)v[1], (_Float16)v[2], (_Float16)v[3]};
        wf1 = f16x4{(_Float16)v[4], (_Float16)v[5], (_Float16)v[6], (_Float16)v[7]};
        float h[8];
#pragma unroll
        for (int j = 0; j < 8; ++j) {
            int idx = 8 * g + j - ln;
            int ci = idx < 0 ? 0 : (idx > 10 ? 10 : idx);
            float t = w1s[ci];
            h[j] = (idx >= 0 && idx <= 10) ? t : 0.f;
        }
        wh = f16x8{(_Float16)h[0], (_Float16)h[1], (_Float16)h[2], (_Float16)h[3],
                   (_Float16)h[4], (_Float16)h[5], (_Float16)h[6], (_Float16)h[7]};
    }

    float lsum = 0.f;
    const int ox = gx0 + 16 * nt + ln;

    // ---- compute one 64x64 region from LDS (R17-validated loop) ----
#define COMP_H(HF, MT, IT)                                                    \
        {                                                                     \
            f32x4 z = {0, 0, 0, 0};                                           \
            int rrow = ln + 16 * (MT) + 32 * (IT); if (rrow > 73) rrow = 73;  \
            const f16x8 rA = *(const f16x8*)(sr + rrow * SSTR + 16 * nt + 8 * g); \
            const f16x8 dA = *(const f16x8*)(sd + rrow * SSTR + 16 * nt + 8 * g); \
            f16x8 sA = rA + dA, qA = rA - dA;                                 \
            f16x8 ss = sA * sA, qq = qA * qA;                                 \
            f32x4 a0 = __builtin_amdgcn_mfma_f32_16x16x32_f16(rA, wh, z, 0, 0, 0); \
            f32x4 a1 = __builtin_amdgcn_mfma_f32_16x16x32_f16(dA, wh, z, 0, 0, 0); \
            f32x4 a2 = __builtin_amdgcn_mfma_f32_16x16x32_f16(ss, wh, z, 0, 0, 0); \
            f32x4 a3 = __builtin_amdgcn_mfma_f32_16x16x32_f16(qq, wh, z, 0, 0, 0); \
            HF[0] = cvt4(a0); HF[1] = cvt4(a1); HF[2] = cvt4(a2); HF[3] = cvt4(a3); \
        }
#define COMP_O(HA, HB, MTV, IT, YB)                                           \
        {                                                                     \
            f32x4 z = {0, 0, 0, 0};                                           \
            f32x4 v0 = __builtin_amdgcn_mfma_f32_16x16x16f16(wf0, HA[0], z, 0, 0, 0); \
            f32x4 v1 = __builtin_amdgcn_mfma_f32_16x16x16f16(wf0, HA[1], z, 0, 0, 0); \
            f32x4 v2 = __builtin_amdgcn_mfma_f32_16x16x16f16(wf0, HA[2], z, 0, 0, 0); \
            f32x4 v3 = __builtin_amdgcn_mfma_f32_16x16x16f16(wf0, HA[3], z, 0, 0, 0); \
            v0 = __builtin_amdgcn_mfma_f32_16x16x16f16(wf1, HB[0], v0, 0, 0, 0); \
            v1 = __builtin_amdgcn_mfma_f32_16x16x16f16(wf1, HB[1], v1, 0, 0, 0); \
            v2 = __builtin_amdgcn_mfma_f32_16x16x16f16(wf1, HB[2], v2, 0, 0, 0); \
            v3 = __builtin_amdgcn_mfma_f32_16x16x16f16(wf1, HB[3], v3, 0, 0, 0); \
            int oy0 = (YB) + 32 * (IT) + 16 * (MTV) + 4 * g;                  \
            if (ox < 502) {                                                   \
                _Pragma("unroll")                                             \
                for (int p = 0; p < 2; ++p) {                                 \
                    f32x2 m1 = {v0[2*p], v0[2*p+1]};                          \
                    f32x2 m2 = {v1[2*p], v1[2*p+1]};                          \
                    f32x2 A  = {v2[2*p], v2[2*p+1]};                          \
                    f32x2 B  = {v3[2*p], v3[2*p+1]};                          \
                    f32x2 m1s = m1 * m1, m2s = m2 * m2, m12 = m1 * m2;        \
                    f32x2 P = m1s + m2s;                                      \
                    f32x2 num1 = 2.f * m12 + 6.5025f;                         \
                    f32x2 num2 = 0.5f * (A - B) - 2.f * m12 + 58.5225f;       \
                    f32x2 den1 = P + 6.5025f;                                 \
                    f32x2 den2 = 0.5f * (A + B) - P + 58.5225f;               \
                    f32x2 num = num1 * num2, den = den1 * den2;               \
                    if (oy0 + 2*p     < 502) lsum += __fdividef(num[0], den[0]); \
                    if (oy0 + 2*p + 1 < 502) lsum += __fdividef(num[1], den[1]); \
                }                                                             \
            }                                                                 \
        }
#define COMP_REGION(YB)                                                       \
    { _Pragma("unroll")                                                       \
      for (int it = 0; it < 2; ++it) {                                        \
          f16x4 hf0[4], hf1[4], hf2[4];                                       \
          COMP_H(hf0, 0, it)                                                  \
          COMP_H(hf1, 1, it)                                                  \
          COMP_H(hf2, 2, it)                                                  \
          COMP_O(hf0, hf1, 0, it, YB)                                         \
          COMP_O(hf1, hf2, 1, it, YB)                                         \
      } }

    COMP_REGION(yb1)

    __syncthreads();                   // all reads of region-1 LDS done
    WRITE_LDS(fv2)
    __syncthreads();                   // region-2 LDS visible

    COMP_REGION(yb2)

    // ---- wave reduce -> SCATTERED fire-and-forget bucket atomic (R14/R17) ----
#pragma unroll
    for (int off = 32; off; off >>= 1) lsum += __shfl_down(lsum, off);
    if (lane == 0) {
        int bucket = (wg * 4 + wv) & (NBUCKETS - 1);
        atomicAdd(&buckets[bucket], lsum);
    }
}

__global__ void ssim_finalize(const float* __restrict__ buckets,
                              float* __restrict__ out, float inv)
{
    int t = threadIdx.x;
    float s = 0.f;
    for (int i = t; i < NBUCKETS; i += 64) s += buckets[i];
#pragma unroll
    for (int off = 32; off; off >>= 1) s += __shfl_down(s, off);
    if (t == 0) out[0] = s * inv;
}

extern "C" void kernel_launch(void* const* d_in, const int* in_sizes, int n_in,
                              void* d_out, int out_size, void* d_ws, size_t ws_size,
                              hipStream_t stream) {
    const float* raw = (const float*)d_in[0];
    const float* dst = (const float*)d_in[1];
    const float* win = (const float*)d_in[2];
    float* out = (float*)d_out;
    float* ws = (float*)d_ws;

    int nimg = in_sizes[0] / (512 * 512);      // B*C = 48
    float inv = 1.0f / ((float)nimg * 502.f * 502.f);
    int nwg = 32 * nimg;                       // 8 x-tiles * 4 region-pairs per image
    int chunkw = nwg >> 3;                     // per-XCD contiguous run

    hipMemsetAsync(ws, 0, NBUCKETS * sizeof(float), stream);   // zero buckets
    ssim_main<<<nwg, 256, 0, stream>>>(raw, dst, win, ws, chunkw);
    ssim_finalize<<<1, 64, 0, stream>>>(ws, out, inv);
}

// Round 19
// 38.082 us; speedup vs baseline: 1.0966x; 1.0966x over previous
//
#include <hip/hip_runtime.h>

typedef _Float16 f16x4 __attribute__((ext_vector_type(4)));
typedef _Float16 f16x8 __attribute__((ext_vector_type(8)));
typedef __fp16 fp16x2 __attribute__((ext_vector_type(2)));   // cvt_pkrtz return type
typedef float f32x4 __attribute__((ext_vector_type(4)));
typedef float f32x2 __attribute__((ext_vector_type(2)));

#define NBUCKETS 256
#define SSTR 88              // row stride in halves (16B-aligned rows for b128)
#define NROWS 74             // staged rows (64 outputs + 10 halo)
#define NPT 6                // staging pair-tasks per thread (1480/256 = 5.8)

__device__ __forceinline__ f16x4 cvt4(f32x4 a)
{
    union { fp16x2 h2[2]; f16x4 f; } u;
    u.h2[0] = __builtin_amdgcn_cvt_pkrtz(a[0], a[1]);
    u.h2[1] = __builtin_amdgcn_cvt_pkrtz(a[2], a[3]);
    return u.f;
}

// ---- main: 64x64 output region per block (2 x 64x32 tiles), 4 waves, ONE barrier.
// H-pass: one mfma_f32_16x16x32_f16 per quantity; D-frag (row=4g+j) feeds vertical
// 16x16x16 B-frags directly in registers (validated R3/R5-R18).
// Quantities: mu1, mu2, A=conv((r+d)^2), B=conv((r-d)^2). Weights in-block (R15+).
// Scattered per-wave bucket atomics (R14/R17). XCD-bijective swizzle (R17: FETCH 71->49MB).
// R19: paired-chunk staging -- 6 tasks/thread, 2 loads + 1 ds_write_b128 each.
__global__ __launch_bounds__(256, 4) void ssim_main(
    const float* __restrict__ raw, const float* __restrict__ dst,
    const float* __restrict__ win, float* __restrict__ buckets)
{
    __shared__ __align__(16) _Float16 sr[NROWS * SSTR];
    __shared__ __align__(16) _Float16 sd[NROWS * SSTR];
    __shared__ float w1s[11];

    const int tid = threadIdx.x;
    const int wv = tid >> 6;           // wave = 16-wide x-strip
    const int lane = tid & 63;
    const int g = lane >> 4;
    const int ln = lane & 15;
    const int nt = wv;

    // XCD-bijective swizzle: 3072 blocks = 8 XCDs x 384-contiguous runs (R17)
    const int wg = blockIdx.x;
    const int sw = (wg & 7) * 384 + (wg >> 3);
    const int bz = sw >> 6;
    const int bx = sw & 7;
    const int by = (sw >> 3) & 7;

    const int gx0 = bx * 64;
    const int ybase32 = by * 64;                // first input row of the region
    const long ioff = (long)bz * (512 * 512);
    const float* rb = raw + ioff;
    const float* db = dst + ioff;

    // 1D gaussian row-sums -> LDS (11 threads; visibility covered by staging barrier)
    if (tid >= 245) {
        int i = tid - 245;             // 0..10
        float s = 0.f;
#pragma unroll
        for (int j = 0; j < 11; ++j) s += win[i * 11 + j];
        w1s[i] = s;
    }

    // ---- staging: 1480 pair-tasks = 74 rows x {r,d} x 10 chunk-pairs.
    // Task: one decode, 2x dwordx4 load (32B contiguous), pack, 1x ds_write_b128.
    // Phase 1 issues ALL loads (12-deep MLP); fast path (49/64 regions) unclamped.
    float4 fvA[NPT], fvB[NPT];
    const bool fastpath = (gx0 < 448) && (ybase32 < 448);
    if (fastpath) {
#pragma unroll
        for (int k = 0; k < NPT; ++k) {
            int t = tid + 256 * k;
            if (k < NPT - 1 || tid < 200) {
                int pc = t % 10;
                int sub = t / 10;          // 0..147
                int row = sub >> 1;        // 0..73
                const float* src = ((sub & 1) ? db : rb) + (long)(ybase32 + row) * 512 + gx0 + 8 * pc;
                fvA[k] = *reinterpret_cast<const float4*>(src);
                fvB[k] = *reinterpret_cast<const float4*>(src + 4);
            }
        }
    } else {
#pragma unroll
        for (int k = 0; k < NPT; ++k) {
            int t = tid + 256 * k;
            if (k < NPT - 1 || tid < 200) {
                int pc = t % 10;
                int sub = t / 10;
                int row = sub >> 1;
                int gy = ybase32 + row; if (gy > 511) gy = 511;
                int ca = gx0 + 8 * pc;     if (ca > 508) ca = 508;
                int cb = ca + 4;           if (cb > 508) cb = 508;
                const float* rowp = ((sub & 1) ? db : rb) + (long)gy * 512;
                fvA[k] = *reinterpret_cast<const float4*>(rowp + ca);
                fvB[k] = *reinterpret_cast<const float4*>(rowp + cb);
            }
        }
    }
#pragma unroll
    for (int k = 0; k < NPT; ++k) {
        int t = tid + 256 * k;
        if (k < NPT - 1 || tid < 200) {
            int pc = t % 10;
            int sub = t / 10;
            int row = sub >> 1;
            _Float16* dstp = ((sub & 1) ? sd : sr) + row * SSTR + pc * 8;
            union { fp16x2 h2[4]; uint4 u; } pk;
            pk.h2[0] = __builtin_amdgcn_cvt_pkrtz(fvA[k].x, fvA[k].y);
            pk.h2[1] = __builtin_amdgcn_cvt_pkrtz(fvA[k].z, fvA[k].w);
            pk.h2[2] = __builtin_amdgcn_cvt_pkrtz(fvB[k].x, fvB[k].y);
            pk.h2[3] = __builtin_amdgcn_cvt_pkrtz(fvB[k].z, fvB[k].w);
            *reinterpret_cast<uint4*>(dstp) = pk.u;     // ds_write_b128
        }
    }
    __syncthreads();

    // ---- per-lane weight fragments (banded, translation-invariant; R15-validated) ----
    f16x4 wf0, wf1;
    f16x8 wh;
    {
        float v[8];
#pragma unroll
        for (int kk = 0; kk < 2; ++kk) {
            int ib = 4 * g + 16 * kk - ln;
#pragma unroll
            for (int j = 0; j < 4; ++j) {
                int idx = ib + j;
                int ci = idx < 0 ? 0 : (idx > 10 ? 10 : idx);
                float t = w1s[ci];
                v[kk * 4 + j] = (idx >= 0 && idx <= 10) ? t : 0.f;
            }
        }
        wf0 = f16x4{(_Float16)v[0], (_Float16)v[1], (_Float16)v[2], (_Float16)v[3]};
        wf1 = f16x4{(_Float16)v[4], (_Float16)v[5], (_Float16)v[6], (_Float16)v[7]};
        float h[8];
#pragma unroll
        for (int j = 0; j < 8; ++j) {
            int idx = 8 * g + j - ln;
            int ci = idx < 0 ? 0 : (idx > 10 ? 10 : idx);
            float t = w1s[ci];
            h[j] = (idx >= 0 && idx <= 10) ? t : 0.f;
        }
        wh = f16x8{(_Float16)h[0], (_Float16)h[1], (_Float16)h[2], (_Float16)h[3],
                   (_Float16)h[4], (_Float16)h[5], (_Float16)h[6], (_Float16)h[7]};
    }

    float lsum = 0.f;
    const int ox = gx0 + 16 * nt + ln;

#pragma unroll
    for (int it = 0; it < 2; ++it) {
        // ---- horizontal conv: ONE 16x16x32 MFMA per quantity per row-tile ----
        f16x4 hf0[4], hf1[4], hf2[4];
#define COMP_H(HF, MT)                                                        \
        {                                                                     \
            f32x4 z = {0, 0, 0, 0};                                           \
            int rrow = ln + 16 * (MT) + 32 * it; if (rrow > 73) rrow = 73;    \
            const f16x8 rA = *(const f16x8*)(sr + rrow * SSTR + 16 * nt + 8 * g); \
            const f16x8 dA = *(const f16x8*)(sd + rrow * SSTR + 16 * nt + 8 * g); \
            f16x8 sA = rA + dA, qA = rA - dA;                                 \
            f16x8 ss = sA * sA, qq = qA * qA;                                 \
            f32x4 a0 = __builtin_amdgcn_mfma_f32_16x16x32_f16(rA, wh, z, 0, 0, 0); \
            f32x4 a1 = __builtin_amdgcn_mfma_f32_16x16x32_f16(dA, wh, z, 0, 0, 0); \
            f32x4 a2 = __builtin_amdgcn_mfma_f32_16x16x32_f16(ss, wh, z, 0, 0, 0); \
            f32x4 a3 = __builtin_amdgcn_mfma_f32_16x16x32_f16(qq, wh, z, 0, 0, 0); \
            HF[0] = cvt4(a0); HF[1] = cvt4(a1); HF[2] = cvt4(a2); HF[3] = cvt4(a3); \
        }
        COMP_H(hf0, 0)
        COMP_H(hf1, 1)
        COMP_H(hf2, 2)
#undef COMP_H

        // ---- vertical conv (2x 16x16x16, register B-frags) + f32x2 epilogue ----
#define COMP_O(HA, HB, MTV)                                                   \
        {                                                                     \
            f32x4 z = {0, 0, 0, 0};                                           \
            f32x4 v0 = __builtin_amdgcn_mfma_f32_16x16x16f16(wf0, HA[0], z, 0, 0, 0); \
            f32x4 v1 = __builtin_amdgcn_mfma_f32_16x16x16f16(wf0, HA[1], z, 0, 0, 0); \
            f32x4 v2 = __builtin_amdgcn_mfma_f32_16x16x16f16(wf0, HA[2], z, 0, 0, 0); \
            f32x4 v3 = __builtin_amdgcn_mfma_f32_16x16x16f16(wf0, HA[3], z, 0, 0, 0); \
            v0 = __builtin_amdgcn_mfma_f32_16x16x16f16(wf1, HB[0], v0, 0, 0, 0); \
            v1 = __builtin_amdgcn_mfma_f32_16x16x16f16(wf1, HB[1], v1, 0, 0, 0); \
            v2 = __builtin_amdgcn_mfma_f32_16x16x16f16(wf1, HB[2], v2, 0, 0, 0); \
            v3 = __builtin_amdgcn_mfma_f32_16x16x16f16(wf1, HB[3], v3, 0, 0, 0); \
            int oy0 = ybase32 + 32 * it + 16 * (MTV) + 4 * g;                 \
            if (ox < 502) {                                                   \
                _Pragma("unroll")                                             \
                for (int p = 0; p < 2; ++p) {                                 \
                    f32x2 m1 = {v0[2*p], v0[2*p+1]};                          \
                    f32x2 m2 = {v1[2*p], v1[2*p+1]};                          \
                    f32x2 A  = {v2[2*p], v2[2*p+1]};                          \
                    f32x2 B  = {v3[2*p], v3[2*p+1]};                          \
                    f32x2 m1s = m1 * m1, m2s = m2 * m2, m12 = m1 * m2;        \
                    f32x2 P = m1s + m2s;                                      \
                    f32x2 num1 = 2.f * m12 + 6.5025f;                         \
                    f32x2 num2 = 0.5f * (A - B) - 2.f * m12 + 58.5225f;       \
                    f32x2 den1 = P + 6.5025f;                                 \
                    f32x2 den2 = 0.5f * (A + B) - P + 58.5225f;               \
                    f32x2 num = num1 * num2, den = den1 * den2;               \
                    if (oy0 + 2*p     < 502) lsum += __fdividef(num[0], den[0]); \
                    if (oy0 + 2*p + 1 < 502) lsum += __fdividef(num[1], den[1]); \
                }                                                             \
            }                                                                 \
        }
        COMP_O(hf0, hf1, 0)
        COMP_O(hf1, hf2, 1)
#undef COMP_O
    }

    // ---- wave reduce -> SCATTERED fire-and-forget bucket atomic (R14/R17) ----
#pragma unroll
    for (int off = 32; off; off >>= 1) lsum += __shfl_down(lsum, off);
    if (lane == 0) {
        int bucket = (wg * 4 + wv) & (NBUCKETS - 1);
        atomicAdd(&buckets[bucket], lsum);
    }
}

__global__ void ssim_finalize(const float* __restrict__ buckets,
                              float* __restrict__ out, float inv)
{
    int t = threadIdx.x;
    float s = 0.f;
    for (int i = t; i < NBUCKETS; i += 64) s += buckets[i];
#pragma unroll
    for (int off = 32; off; off >>= 1) s += __shfl_down(s, off);
    if (t == 0) out[0] = s * inv;
}

extern "C" void kernel_launch(void* const* d_in, const int* in_sizes, int n_in,
                              void* d_out, int out_size, void* d_ws, size_t ws_size,
                              hipStream_t stream) {
    const float* raw = (const float*)d_in[0];
    const float* dst = (const float*)d_in[1];
    const float* win = (const float*)d_in[2];
    float* out = (float*)d_out;
    float* ws = (float*)d_ws;

    int nimg = in_sizes[0] / (512 * 512);      // B*C = 48
    float inv = 1.0f / ((float)nimg * 502.f * 502.f);
    int nwg = 64 * nimg;                       // 8x8 regions per image

    hipMemsetAsync(ws, 0, NBUCKETS * sizeof(float), stream);   // zero buckets
    ssim_main<<<nwg, 256, 0, stream>>>(raw, dst, win, ws);
    ssim_finalize<<<1, 64, 0, stream>>>(ws, out, inv);
}

// Round 20
// 31.460 us; speedup vs baseline: 1.3275x; 1.2105x over previous
//
#include <hip/hip_runtime.h>

typedef _Float16 f16x4 __attribute__((ext_vector_type(4)));
typedef _Float16 f16x8 __attribute__((ext_vector_type(8)));
typedef __fp16 fp16x2 __attribute__((ext_vector_type(2)));   // cvt_pkrtz return type
typedef float f32x4 __attribute__((ext_vector_type(4)));
typedef float f32x2 __attribute__((ext_vector_type(2)));

#define SSTR 88              // row stride in halves (16B-aligned rows for b128)
#define NROWS 74             // staged rows (64 outputs + 10 halo)
#define NPT 6                // staging pair-tasks per thread (1480/256 = 5.8)

__device__ __forceinline__ f16x4 cvt4(f32x4 a)
{
    union { fp16x2 h2[2]; f16x4 f; } u;
    u.h2[0] = __builtin_amdgcn_cvt_pkrtz(a[0], a[1]);
    u.h2[1] = __builtin_amdgcn_cvt_pkrtz(a[2], a[3]);
    return u.f;
}

// ---- main: 64x64 output region per block (2 x 64x32 tiles), 4 waves, ONE barrier.
// H-pass: one mfma_f32_16x16x32_f16 per quantity; D-frag (row=4g+j) feeds vertical
// 16x16x16 B-frags directly in registers (validated R3/R5-R19).
// Quantities: mu1, mu2, A=conv((r+d)^2), B=conv((r-d)^2). Weights in-block (R15+).
// XCD-bijective swizzle (R17: FETCH 71->49MB). Paired-chunk staging (R19).
// R20: per-(block,wave) PLAIN-STORE bucket slots -- no atomics, no zeroing memset.
__global__ __launch_bounds__(256, 4) void ssim_main(
    const float* __restrict__ raw, const float* __restrict__ dst,
    const float* __restrict__ win, float* __restrict__ buckets)
{
    __shared__ __align__(16) _Float16 sr[NROWS * SSTR];
    __shared__ __align__(16) _Float16 sd[NROWS * SSTR];
    __shared__ float w1s[11];

    const int tid = threadIdx.x;
    const int wv = tid >> 6;           // wave = 16-wide x-strip
    const int lane = tid & 63;
    const int g = lane >> 4;
    const int ln = lane & 15;
    const int nt = wv;

    // XCD-bijective swizzle: 3072 blocks = 8 XCDs x 384-contiguous runs (R17)
    const int wg = blockIdx.x;
    const int sw = (wg & 7) * 384 + (wg >> 3);
    const int bz = sw >> 6;
    const int bx = sw & 7;
    const int by = (sw >> 3) & 7;

    const int gx0 = bx * 64;
    const int ybase32 = by * 64;                // first input row of the region
    const long ioff = (long)bz * (512 * 512);
    const float* rb = raw + ioff;
    const float* db = dst + ioff;

    // 1D gaussian row-sums -> LDS (11 threads; visibility covered by staging barrier)
    if (tid >= 245) {
        int i = tid - 245;             // 0..10
        float s = 0.f;
#pragma unroll
        for (int j = 0; j < 11; ++j) s += win[i * 11 + j];
        w1s[i] = s;
    }

    // ---- staging: 1480 pair-tasks = 74 rows x {r,d} x 10 chunk-pairs (R19).
    // Task: one decode, 2x dwordx4 load (32B contiguous), pack, 1x ds_write_b128.
    float4 fvA[NPT], fvB[NPT];
    const bool fastpath = (gx0 < 448) && (ybase32 < 448);
    if (fastpath) {
#pragma unroll
        for (int k = 0; k < NPT; ++k) {
            int t = tid + 256 * k;
            if (k < NPT - 1 || tid < 200) {
                int pc = t % 10;
                int sub = t / 10;          // 0..147
                int row = sub >> 1;        // 0..73
                const float* src = ((sub & 1) ? db : rb) + (long)(ybase32 + row) * 512 + gx0 + 8 * pc;
                fvA[k] = *reinterpret_cast<const float4*>(src);
                fvB[k] = *reinterpret_cast<const float4*>(src + 4);
            }
        }
    } else {
#pragma unroll
        for (int k = 0; k < NPT; ++k) {
            int t = tid + 256 * k;
            if (k < NPT - 1 || tid < 200) {
                int pc = t % 10;
                int sub = t / 10;
                int row = sub >> 1;
                int gy = ybase32 + row; if (gy > 511) gy = 511;
                int ca = gx0 + 8 * pc;     if (ca > 508) ca = 508;
                int cb = ca + 4;           if (cb > 508) cb = 508;
                const float* rowp = ((sub & 1) ? db : rb) + (long)gy * 512;
                fvA[k] = *reinterpret_cast<const float4*>(rowp + ca);
                fvB[k] = *reinterpret_cast<const float4*>(rowp + cb);
            }
        }
    }
#pragma unroll
    for (int k = 0; k < NPT; ++k) {
        int t = tid + 256 * k;
        if (k < NPT - 1 || tid < 200) {
            int pc = t % 10;
            int sub = t / 10;
            int row = sub >> 1;
            _Float16* dstp = ((sub & 1) ? sd : sr) + row * SSTR + pc * 8;
            union { fp16x2 h2[4]; uint4 u; } pk;
            pk.h2[0] = __builtin_amdgcn_cvt_pkrtz(fvA[k].x, fvA[k].y);
            pk.h2[1] = __builtin_amdgcn_cvt_pkrtz(fvA[k].z, fvA[k].w);
            pk.h2[2] = __builtin_amdgcn_cvt_pkrtz(fvB[k].x, fvB[k].y);
            pk.h2[3] = __builtin_amdgcn_cvt_pkrtz(fvB[k].z, fvB[k].w);
            *reinterpret_cast<uint4*>(dstp) = pk.u;     // ds_write_b128
        }
    }
    __syncthreads();

    // ---- per-lane weight fragments (banded, translation-invariant; R15-validated) ----
    f16x4 wf0, wf1;
    f16x8 wh;
    {
        float v[8];
#pragma unroll
        for (int kk = 0; kk < 2; ++kk) {
            int ib = 4 * g + 16 * kk - ln;
#pragma unroll
            for (int j = 0; j < 4; ++j) {
                int idx = ib + j;
                int ci = idx < 0 ? 0 : (idx > 10 ? 10 : idx);
                float t = w1s[ci];
                v[kk * 4 + j] = (idx >= 0 && idx <= 10) ? t : 0.f;
            }
        }
        wf0 = f16x4{(_Float16)v[0], (_Float16)v[1], (_Float16)v[2], (_Float16)v[3]};
        wf1 = f16x4{(_Float16)v[4], (_Float16)v[5], (_Float16)v[6], (_Float16)v[7]};
        float h[8];
#pragma unroll
        for (int j = 0; j < 8; ++j) {
            int idx = 8 * g + j - ln;
            int ci = idx < 0 ? 0 : (idx > 10 ? 10 : idx);
            float t = w1s[ci];
            h[j] = (idx >= 0 && idx <= 10) ? t : 0.f;
        }
        wh = f16x8{(_Float16)h[0], (_Float16)h[1], (_Float16)h[2], (_Float16)h[3],
                   (_Float16)h[4], (_Float16)h[5], (_Float16)h[6], (_Float16)h[7]};
    }

    float lsum = 0.f;
    const int ox = gx0 + 16 * nt + ln;

#pragma unroll
    for (int it = 0; it < 2; ++it) {
        // ---- horizontal conv: ONE 16x16x32 MFMA per quantity per row-tile ----
        f16x4 hf0[4], hf1[4], hf2[4];
#define COMP_H(HF, MT)                                                        \
        {                                                                     \
            f32x4 z = {0, 0, 0, 0};                                           \
            int rrow = ln + 16 * (MT) + 32 * it; if (rrow > 73) rrow = 73;    \
            const f16x8 rA = *(const f16x8*)(sr + rrow * SSTR + 16 * nt + 8 * g); \
            const f16x8 dA = *(const f16x8*)(sd + rrow * SSTR + 16 * nt + 8 * g); \
            f16x8 sA = rA + dA, qA = rA - dA;                                 \
            f16x8 ss = sA * sA, qq = qA * qA;                                 \
            f32x4 a0 = __builtin_amdgcn_mfma_f32_16x16x32_f16(rA, wh, z, 0, 0, 0); \
            f32x4 a1 = __builtin_amdgcn_mfma_f32_16x16x32_f16(dA, wh, z, 0, 0, 0); \
            f32x4 a2 = __builtin_amdgcn_mfma_f32_16x16x32_f16(ss, wh, z, 0, 0, 0); \
            f32x4 a3 = __builtin_amdgcn_mfma_f32_16x16x32_f16(qq, wh, z, 0, 0, 0); \
            HF[0] = cvt4(a0); HF[1] = cvt4(a1); HF[2] = cvt4(a2); HF[3] = cvt4(a3); \
        }
        COMP_H(hf0, 0)
        COMP_H(hf1, 1)
        COMP_H(hf2, 2)
#undef COMP_H

        // ---- vertical conv (2x 16x16x16, register B-frags) + f32x2 epilogue ----
#define COMP_O(HA, HB, MTV)                                                   \
        {                                                                     \
            f32x4 z = {0, 0, 0, 0};                                           \
            f32x4 v0 = __builtin_amdgcn_mfma_f32_16x16x16f16(wf0, HA[0], z, 0, 0, 0); \
            f32x4 v1 = __builtin_amdgcn_mfma_f32_16x16x16f16(wf0, HA[1], z, 0, 0, 0); \
            f32x4 v2 = __builtin_amdgcn_mfma_f32_16x16x16f16(wf0, HA[2], z, 0, 0, 0); \
            f32x4 v3 = __builtin_amdgcn_mfma_f32_16x16x16f16(wf0, HA[3], z, 0, 0, 0); \
            v0 = __builtin_amdgcn_mfma_f32_16x16x16f16(wf1, HB[0], v0, 0, 0, 0); \
            v1 = __builtin_amdgcn_mfma_f32_16x16x16f16(wf1, HB[1], v1, 0, 0, 0); \
            v2 = __builtin_amdgcn_mfma_f32_16x16x16f16(wf1, HB[2], v2, 0, 0, 0); \
            v3 = __builtin_amdgcn_mfma_f32_16x16x16f16(wf1, HB[3], v3, 0, 0, 0); \
            int oy0 = ybase32 + 32 * it + 16 * (MTV) + 4 * g;                 \
            if (ox < 502) {                                                   \
                _Pragma("unroll")                                             \
                for (int p = 0; p < 2; ++p) {                                 \
                    f32x2 m1 = {v0[2*p], v0[2*p+1]};                          \
                    f32x2 m2 = {v1[2*p], v1[2*p+1]};                          \
                    f32x2 A  = {v2[2*p], v2[2*p+1]};                          \
                    f32x2 B  = {v3[2*p], v3[2*p+1]};                          \
                    f32x2 m1s = m1 * m1, m2s = m2 * m2, m12 = m1 * m2;        \
                    f32x2 P = m1s + m2s;                                      \
                    f32x2 num1 = 2.f * m12 + 6.5025f;                         \
                    f32x2 num2 = 0.5f * (A - B) - 2.f * m12 + 58.5225f;       \
                    f32x2 den1 = P + 6.5025f;                                 \
                    f32x2 den2 = 0.5f * (A + B) - P + 58.5225f;               \
                    f32x2 num = num1 * num2, den = den1 * den2;               \
                    if (oy0 + 2*p     < 502) lsum += __fdividef(num[0], den[0]); \
                    if (oy0 + 2*p + 1 < 502) lsum += __fdividef(num[1], den[1]); \
                }                                                             \
            }                                                                 \
        }
        COMP_O(hf0, hf1, 0)
        COMP_O(hf1, hf2, 1)
#undef COMP_O
    }

    // ---- wave reduce -> PLAIN STORE to unique slot (no atomics, no memset) ----
#pragma unroll
    for (int off = 32; off; off >>= 1) lsum += __shfl_down(lsum, off);
    if (lane == 0) buckets[wg * 4 + wv] = lsum;
}

// finalize: sum nwg*4 slots (as nwg float4s), 256 threads
__global__ __launch_bounds__(256) void ssim_finalize(
    const float* __restrict__ buckets, float* __restrict__ out,
    float inv, int n4)
{
    __shared__ float sred[4];
    int tid = threadIdx.x;
    float s = 0.f;
    const float4* b4 = (const float4*)buckets;
    for (int i = tid; i < n4; i += 256) {
        float4 v = b4[i];
        s += (v.x + v.y) + (v.z + v.w);
    }
#pragma unroll
    for (int off = 32; off; off >>= 1) s += __shfl_down(s, off);
    if ((tid & 63) == 0) sred[tid >> 6] = s;
    __syncthreads();
    if (tid == 0) out[0] = ((sred[0] + sred[1]) + (sred[2] + sred[3])) * inv;
}

extern "C" void kernel_launch(void* const* d_in, const int* in_sizes, int n_in,
                              void* d_out, int out_size, void* d_ws, size_t ws_size,
                              hipStream_t stream) {
    const float* raw = (const float*)d_in[0];
    const float* dst = (const float*)d_in[1];
    const float* win = (const float*)d_in[2];
    float* out = (float*)d_out;
    float* ws = (float*)d_ws;

    int nimg = in_sizes[0] / (512 * 512);      // B*C = 48
    float inv = 1.0f / ((float)nimg * 502.f * 502.f);
    int nwg = 64 * nimg;                       // 8x8 regions per image

    ssim_main<<<nwg, 256, 0, stream>>>(raw, dst, win, ws);
    ssim_finalize<<<1, 256, 0, stream>>>(ws, out, inv, nwg);
}

// Round 21
// 30.847 us; speedup vs baseline: 1.3538x; 1.0198x over previous
//
#include <hip/hip_runtime.h>

typedef _Float16 f16x4 __attribute__((ext_vector_type(4)));
typedef _Float16 f16x8 __attribute__((ext_vector_type(8)));
typedef __fp16 fp16x2 __attribute__((ext_vector_type(2)));   // cvt_pkrtz return type
typedef float f32x4 __attribute__((ext_vector_type(4)));
typedef float f32x2 __attribute__((ext_vector_type(2)));

#define SSTR 88              // row stride in halves (16B-aligned rows for b128)
#define NROWS 74             // staged rows (64 outputs + 10 halo)
#define NPT 6                // staging pair-tasks per thread (1480/256 = 5.8)

__device__ __forceinline__ f16x4 cvt4(f32x4 a)
{
    union { fp16x2 h2[2]; f16x4 f; } u;
    u.h2[0] = __builtin_amdgcn_cvt_pkrtz(a[0], a[1]);
    u.h2[1] = __builtin_amdgcn_cvt_pkrtz(a[2], a[3]);
    return u.f;
}

// ---- main: 64x64 output region per block (2 x 64x32 tiles), 4 waves, ONE barrier.
// H-pass: one mfma_f32_16x16x32_f16 per quantity; D-frag (row=4g+j) feeds vertical
// 16x16x16 B-frags directly in registers (validated R3/R5-R20).
// Quantities: mu1, mu2, A=conv((r+d)^2), B=conv((r-d)^2).
// XCD-bijective swizzle (R17). Paired-chunk staging (R19). Plain-store buckets (R20).
// R21: weight frags via 4 rotation-padded f16 LDS copies of w1 -> 3-4 aligned
// ds_read_b64 per lane instead of ~110 VALU clamp/select insts.
__global__ __launch_bounds__(256, 4) void ssim_main(
    const float* __restrict__ raw, const float* __restrict__ dst,
    const float* __restrict__ win, float* __restrict__ buckets)
{
    __shared__ __align__(16) _Float16 sr[NROWS * SSTR];
    __shared__ __align__(16) _Float16 sd[NROWS * SSTR];
    __shared__ __align__(16) _Float16 wrot[4][64];   // wrot[r][i] = w1[i+r-16] (0 outside)

    const int tid = threadIdx.x;
    const int wv = tid >> 6;           // wave = 16-wide x-strip
    const int lane = tid & 63;
    const int g = lane >> 4;
    const int ln = lane & 15;
    const int nt = wv;

    // XCD-bijective swizzle: 3072 blocks = 8 XCDs x 384-contiguous runs (R17)
    const int wg = blockIdx.x;
    const int sw = (wg & 7) * 384 + (wg >> 3);
    const int bz = sw >> 6;
    const int bx = sw & 7;
    const int by = (sw >> 3) & 7;

    const int gx0 = bx * 64;
    const int ybase32 = by * 64;                // first input row of the region
    const long ioff = (long)bz * (512 * 512);
    const float* rb = raw + ioff;
    const float* db = dst + ioff;

    // ---- staging: 1480 pair-tasks = 74 rows x {r,d} x 10 chunk-pairs (R19).
    // Task: one decode, 2x dwordx4 load (32B contiguous), pack, 1x ds_write_b128.
    // LDS write pointers hoisted into registers (computed once in the load loop).
    float4 fvA[NPT], fvB[NPT];
    _Float16* dsts[NPT];
    const bool fastpath = (gx0 < 448) && (ybase32 < 448);
    if (fastpath) {
#pragma unroll
        for (int k = 0; k < NPT; ++k) {
            int t = tid + 256 * k;
            if (k < NPT - 1 || tid < 200) {
                int pc = t % 10;
                int sub = t / 10;          // 0..147
                int row = sub >> 1;        // 0..73
                const float* src = ((sub & 1) ? db : rb) + (long)(ybase32 + row) * 512 + gx0 + 8 * pc;
                fvA[k] = *reinterpret_cast<const float4*>(src);
                fvB[k] = *reinterpret_cast<const float4*>(src + 4);
                dsts[k] = ((sub & 1) ? sd : sr) + row * SSTR + pc * 8;
            } else {
                dsts[k] = nullptr;
            }
        }
    } else {
#pragma unroll
        for (int k = 0; k < NPT; ++k) {
            int t = tid + 256 * k;
            if (k < NPT - 1 || tid < 200) {
                int pc = t % 10;
                int sub = t / 10;
                int row = sub >> 1;
                int gy = ybase32 + row; if (gy > 511) gy = 511;
                int ca = gx0 + 8 * pc;     if (ca > 508) ca = 508;
                int cb = ca + 4;           if (cb > 508) cb = 508;
                const float* rowp = ((sub & 1) ? db : rb) + (long)gy * 512;
                fvA[k] = *reinterpret_cast<const float4*>(rowp + ca);
                fvB[k] = *reinterpret_cast<const float4*>(rowp + cb);
                dsts[k] = ((sub & 1) ? sd : sr) + row * SSTR + pc * 8;
            } else {
                dsts[k] = nullptr;
            }
        }
    }

    // ---- rotated padded weight copies (pre-barrier; hides under staging loads) ----
    {
        int r = tid >> 6, i = tid & 63;
        int idx = i + r - 16;
        float val = 0.f;
        if (idx >= 0 && idx <= 10) {
#pragma unroll
            for (int j = 0; j < 11; ++j) val += win[idx * 11 + j];
        }
        wrot[r][i] = (_Float16)val;
    }

#pragma unroll
    for (int k = 0; k < NPT; ++k) {
        if (dsts[k]) {
            union { fp16x2 h2[4]; uint4 u; } pk;
            pk.h2[0] = __builtin_amdgcn_cvt_pkrtz(fvA[k].x, fvA[k].y);
            pk.h2[1] = __builtin_amdgcn_cvt_pkrtz(fvA[k].z, fvA[k].w);
            pk.h2[2] = __builtin_amdgcn_cvt_pkrtz(fvB[k].x, fvB[k].y);
            pk.h2[3] = __builtin_amdgcn_cvt_pkrtz(fvB[k].z, fvB[k].w);
            *reinterpret_cast<uint4*>(dsts[k]) = pk.u;     // ds_write_b128
        }
    }
    __syncthreads();

    // ---- weight fragments via aligned LDS reads (banded, translation-invariant) ----
    // wf element (kk,j) = w1[4g+16kk+j-ln] = padded[s+16kk+j], s = 4g-ln+16.
    // Rotation copy r=s&3 puts padded[s..] at 8B-aligned (s>>2)*8.
    f16x4 wf0, wf1;
    f16x8 wh;
    {
        int s = 4 * g - ln + 16;               // 1..28
        const char* b0 = (const char*)wrot[s & 3] + (s >> 2) * 8;
        wf0 = *(const f16x4*)(b0);
        wf1 = *(const f16x4*)(b0 + 32);        // +16 halves, same rotation
        int s2 = 8 * g - ln + 16;              // 1..40
        const char* b2 = (const char*)wrot[s2 & 3] + (s2 >> 2) * 8;
        union { f16x4 q[2]; f16x8 o; } uu;
        uu.q[0] = *(const f16x4*)(b2);
        uu.q[1] = *(const f16x4*)(b2 + 8);
        wh = uu.o;
    }

    float lsum = 0.f;
    const int ox = gx0 + 16 * nt + ln;

#pragma unroll
    for (int it = 0; it < 2; ++it) {
        // ---- horizontal conv: ONE 16x16x32 MFMA per quantity per row-tile ----
        f16x4 hf0[4], hf1[4], hf2[4];
#define COMP_H(HF, MT)                                                        \
        {                                                                     \
            f32x4 z = {0, 0, 0, 0};                                           \
            int rrow = ln + 16 * (MT) + 32 * it; if (rrow > 73) rrow = 73;    \
            const f16x8 rA = *(const f16x8*)(sr + rrow * SSTR + 16 * nt + 8 * g); \
            const f16x8 dA = *(const f16x8*)(sd + rrow * SSTR + 16 * nt + 8 * g); \
            f16x8 sA = rA + dA, qA = rA - dA;                                 \
            f16x8 ss = sA * sA, qq = qA * qA;                                 \
            f32x4 a0 = __builtin_amdgcn_mfma_f32_16x16x32_f16(rA, wh, z, 0, 0, 0); \
            f32x4 a1 = __builtin_amdgcn_mfma_f32_16x16x32_f16(dA, wh, z, 0, 0, 0); \
            f32x4 a2 = __builtin_amdgcn_mfma_f32_16x16x32_f16(ss, wh, z, 0, 0, 0); \
            f32x4 a3 = __builtin_amdgcn_mfma_f32_16x16x32_f16(qq, wh, z, 0, 0, 0); \
            HF[0] = cvt4(a0); HF[1] = cvt4(a1); HF[2] = cvt4(a2); HF[3] = cvt4(a3); \
        }
        COMP_H(hf0, 0)
        COMP_H(hf1, 1)
        COMP_H(hf2, 2)
#undef COMP_H

        // ---- vertical conv (2x 16x16x16, register B-frags) + f32x2 epilogue ----
#define COMP_O(HA, HB, MTV)                                                   \
        {                                                                     \
            f32x4 z = {0, 0, 0, 0};                                           \
            f32x4 v0 = __builtin_amdgcn_mfma_f32_16x16x16f16(wf0, HA[0], z, 0, 0, 0); \
            f32x4 v1 = __builtin_amdgcn_mfma_f32_16x16x16f16(wf0, HA[1], z, 0, 0, 0); \
            f32x4 v2 = __builtin_amdgcn_mfma_f32_16x16x16f16(wf0, HA[2], z, 0, 0, 0); \
            f32x4 v3 = __builtin_amdgcn_mfma_f32_16x16x16f16(wf0, HA[3], z, 0, 0, 0); \
            v0 = __builtin_amdgcn_mfma_f32_16x16x16f16(wf1, HB[0], v0, 0, 0, 0); \
            v1 = __builtin_amdgcn_mfma_f32_16x16x16f16(wf1, HB[1], v1, 0, 0, 0); \
            v2 = __builtin_amdgcn_mfma_f32_16x16x16f16(wf1, HB[2], v2, 0, 0, 0); \
            v3 = __builtin_amdgcn_mfma_f32_16x16x16f16(wf1, HB[3], v3, 0, 0, 0); \
            int oy0 = ybase32 + 32 * it + 16 * (MTV) + 4 * g;                 \
            if (ox < 502) {                                                   \
                _Pragma("unroll")                                             \
                for (int p = 0; p < 2; ++p) {                                 \
                    f32x2 m1 = {v0[2*p], v0[2*p+1]};                          \
                    f32x2 m2 = {v1[2*p], v1[2*p+1]};                          \
                    f32x2 A  = {v2[2*p], v2[2*p+1]};                          \
                    f32x2 B  = {v3[2*p], v3[2*p+1]};                          \
                    f32x2 m1s = m1 * m1, m2s = m2 * m2, m12 = m1 * m2;        \
                    f32x2 P = m1s + m2s;                                      \
                    f32x2 num1 = 2.f * m12 + 6.5025f;                         \
                    f32x2 num2 = 0.5f * (A - B) - 2.f * m12 + 58.5225f;       \
                    f32x2 den1 = P + 6.5025f;                                 \
                    f32x2 den2 = 0.5f * (A + B) - P + 58.5225f;               \
                    f32x2 num = num1 * num2, den = den1 * den2;               \
                    if (oy0 + 2*p     < 502) lsum += __fdividef(num[0], den[0]); \
                    if (oy0 + 2*p + 1 < 502) lsum += __fdividef(num[1], den[1]); \
                }                                                             \
            }                                                                 \
        }
        COMP_O(hf0, hf1, 0)
        COMP_O(hf1, hf2, 1)
#undef COMP_O
    }

    // ---- wave reduce -> PLAIN STORE to unique slot (no atomics, no memset) ----
#pragma unroll
    for (int off = 32; off; off >>= 1) lsum += __shfl_down(lsum, off);
    if (lane == 0) buckets[wg * 4 + wv] = lsum;
}

// finalize: sum nwg*4 slots (as nwg float4s), 256 threads
__global__ __launch_bounds__(256) void ssim_finalize(
    const float* __restrict__ buckets, float* __restrict__ out,
    float inv, int n4)
{
    __shared__ float sred[4];
    int tid = threadIdx.x;
    float s = 0.f;
    const float4* b4 = (const float4*)buckets;
    for (int i = tid; i < n4; i += 256) {
        float4 v = b4[i];
        s += (v.x + v.y) + (v.z + v.w);
    }
#pragma unroll
    for (int off = 32; off; off >>= 1) s += __shfl_down(s, off);
    if ((tid & 63) == 0) sred[tid >> 6] = s;
    __syncthreads();
    if (tid == 0) out[0] = ((sred[0] + sred[1]) + (sred[2] + sred[3])) * inv;
}

extern "C" void kernel_launch(void* const* d_in, const int* in_sizes, int n_in,
                              void* d_out, int out_size, void* d_ws, size_t ws_size,
                              hipStream_t stream) {
    const float* raw = (const float*)d_in[0];
    const float* dst = (const float*)d_in[1];
    const float* win = (const float*)d_in[2];
    float* out = (float*)d_out;
    float* ws = (float*)d_ws;

    int nimg = in_sizes[0] / (512 * 512);      // B*C = 48
    float inv = 1.0f / ((float)nimg * 502.f * 502.f);
    int nwg = 64 * nimg;                       // 8x8 regions per image

    ssim_main<<<nwg, 256, 0, stream>>>(raw, dst, win, ws);
    ssim_finalize<<<1, 256, 0, stream>>>(ws, out, inv, nwg);
}